// Round 1
// baseline (74.537 us; speedup 1.0000x reference)
//
#include <hip/hip_runtime.h>
#include <hip/hip_bf16.h>
#include <float.h>

#define TSEQ  8192
#define EDIM  64
#define BS    128
#define NHEAD 8

typedef __attribute__((ext_vector_type(8))) short bf16x8;
typedef __attribute__((ext_vector_type(4))) float f32x4;

__device__ __forceinline__ unsigned short bfbits(float f) {
    unsigned int u = __float_as_uint(f);
    u += 0x7fffu + ((u >> 16) & 1u);   // RNE to bf16
    return (unsigned short)(u >> 16);
}
__device__ __forceinline__ float bf2f(unsigned short s) {
    return __uint_as_float(((unsigned int)s) << 16);
}

// XOR-swizzles (T2): keep 8-element k-chunks contiguous & 16B aligned, spread banks.
__device__ __forceinline__ int swz64(int r, int c)  { return (r << 6) + (c ^ ((r & 7) << 3)); }   // [*][64]
__device__ __forceinline__ int swzE(int rr, int i)  { return (rr << 7) + (i ^ ((rr & 7) << 3)); } // emb col-major [256][128]
__device__ __forceinline__ int swzP(int i, int j)   { return (i << 8) + (j ^ ((i & 7) << 3)); }   // P row-major [128][256]
__device__ __forceinline__ int swzV(int c, int kk)  { return (c << 8) + (kk ^ ((c & 7) << 3)); }  // V^T [64][256]

__device__ __forceinline__ f32x4 mfma16(bf16x8 a, bf16x8 b, f32x4 c) {
    return __builtin_amdgcn_mfma_f32_16x16x32_bf16(a, b, c, 0, 0, 0);
}

__global__ __launch_bounds__(512)
void local_attn_kernel(const float* __restrict__ qg, const float* __restrict__ kg,
                       const float* __restrict__ vg, const float* __restrict__ rwg,
                       float* __restrict__ outg)
{
    __shared__ __align__(16) unsigned short sQ[BS * EDIM];       // 16 KB  q (scaled, bf16)
    __shared__ __align__(16) unsigned short sB[2 * BS * EDIM];   // 32 KB  RW, then K_norm
    __shared__ __align__(16) unsigned short sE[BS * 2 * BS];     // 64 KB  emb (col-major), then P (row-major)
    __shared__ __align__(16) unsigned short sV[EDIM * 2 * BS];   // 32 KB  V^T

    const int tid  = threadIdx.x;
    const int lane = tid & 63;
    const int wv   = tid >> 6;

    // XCD-bijective swizzle: 1024 blocks = 8 XCDs * 128 contiguous logical ids
    const int lb = ((blockIdx.x & 7) << 7) + (blockIdx.x >> 3);
    const int bh = lb >> 6;   // 0..15
    const int n  = lb & 63;   // bucket
    const int h  = bh & 7;

    const float scale = 0.125f;  // 64^-0.5

    const float* Qp = qg + ((size_t)bh * TSEQ + (size_t)n * BS) * EDIM;
    const float* Kp = kg + (size_t)bh * TSEQ * EDIM + ((long)n - 1) * BS * EDIM;
    const float* Vp = vg + (size_t)bh * TSEQ * EDIM + ((long)n - 1) * BS * EDIM;

    const int cr = tid >> 4;          // 0..31 (row within pass)
    const int c0 = (tid & 15) << 2;   // feature group of 4

    // ---- stage Q (pre-scaled) ----
    #pragma unroll
    for (int pp = 0; pp < 4; ++pp) {
        const int i = pp * 32 + cr;
        const f32x4 x = *reinterpret_cast<const f32x4*>(Qp + i * EDIM + c0);
        ushort4 pk = make_ushort4(bfbits(x.x * scale), bfbits(x.y * scale),
                                  bfbits(x.z * scale), bfbits(x.w * scale));
        *reinterpret_cast<ushort4*>(&sQ[swz64(i, c0)]) = pk;
    }
    // ---- stage rel_weights[., h, .] ----
    #pragma unroll
    for (int pp = 0; pp < 8; ++pp) {
        const int r = pp * 32 + cr;
        const f32x4 x = *reinterpret_cast<const f32x4*>(rwg + ((size_t)r * NHEAD + h) * EDIM + c0);
        ushort4 pk = make_ushort4(bfbits(x.x), bfbits(x.y), bfbits(x.z), bfbits(x.w));
        *reinterpret_cast<ushort4*>(&sB[swz64(r, c0)]) = pk;
    }
    // ---- stage V^T (window rows -> columns) ----
    {
        const int vc  = (tid & 31) << 1;
        const int vr0 = tid >> 5;  // 0..15
        #pragma unroll
        for (int pp = 0; pp < 16; ++pp) {
            const int r = pp * 16 + vr0;     // key row in window [0,256)
            float2 x = make_float2(0.f, 0.f);
            if (!(n == 0 && r < BS))
                x = *reinterpret_cast<const float2*>(Vp + r * EDIM + vc);
            sV[swzV(vc,     r)] = bfbits(x.x);
            sV[swzV(vc + 1, r)] = bfbits(x.y);
        }
    }
    // ---- issue K loads early (hide under phase 1) ----
    f32x4 kreg[8];
    #pragma unroll
    for (int pp = 0; pp < 8; ++pp) {
        const int r = pp * 32 + cr;
        if (n == 0 && r < BS) kreg[pp] = f32x4{0.f, 0.f, 0.f, 0.f};
        else kreg[pp] = *reinterpret_cast<const f32x4*>(Kp + r * EDIM + c0);
    }

    __syncthreads();

    const int jlane = lane & 15;
    const int kq0   = (lane >> 4) << 3;              // 0,8,16,24
    const int ibase = wv * 16 + ((lane >> 4) << 2);  // C rows: ibase+0..3
    const int arow  = wv * 16 + jlane;               // A rows

    const bf16x8 aq0 = *reinterpret_cast<const bf16x8*>(&sQ[swz64(arow, kq0)]);
    const bf16x8 aq1 = *reinterpret_cast<const bf16x8*>(&sQ[swz64(arow, 32 + kq0)]);

    // ---- phase 1: emb = q_s * RW^T -> sE (col-major, bf16) ----
    #pragma unroll
    for (int t = 0; t < 16; ++t) {
        const int rr = t * 16 + jlane;
        const bf16x8 b0 = *reinterpret_cast<const bf16x8*>(&sB[swz64(rr, kq0)]);
        const bf16x8 b1 = *reinterpret_cast<const bf16x8*>(&sB[swz64(rr, 32 + kq0)]);
        f32x4 e = {0.f, 0.f, 0.f, 0.f};
        e = mfma16(aq0, b0, e);
        e = mfma16(aq1, b1, e);
        ushort4 pk = make_ushort4(bfbits(e[0]), bfbits(e[1]), bfbits(e[2]), bfbits(e[3]));
        *reinterpret_cast<ushort4*>(&sE[swzE(rr, ibase)]) = pk;  // rows ibase..ibase+3 contiguous
    }

    __syncthreads();  // all RW reads done -> sB reusable

    // ---- K: normalize (fp32) -> sB bf16 ----
    #pragma unroll
    for (int pp = 0; pp < 8; ++pp) {
        const int r = pp * 32 + cr;
        const f32x4 x = kreg[pp];
        float ss = x.x * x.x + x.y * x.y + x.z * x.z + x.w * x.w;
        ss += __shfl_xor(ss, 1);
        ss += __shfl_xor(ss, 2);
        ss += __shfl_xor(ss, 4);
        ss += __shfl_xor(ss, 8);
        const float rn = 1.0f / fmaxf(sqrtf(ss), 1e-12f);
        ushort4 pk = make_ushort4(bfbits(x.x * rn), bfbits(x.y * rn),
                                  bfbits(x.z * rn), bfbits(x.w * rn));
        *reinterpret_cast<ushort4*>(&sB[swz64(r, c0)]) = pk;
    }

    __syncthreads();

    // ---- phase 2: dots = q_s * K_norm^T ----
    f32x4 dots[16];
    #pragma unroll
    for (int t = 0; t < 16; ++t) {
        const int rr = t * 16 + jlane;
        const bf16x8 b0 = *reinterpret_cast<const bf16x8*>(&sB[swz64(rr, kq0)]);
        const bf16x8 b1 = *reinterpret_cast<const bf16x8*>(&sB[swz64(rr, 32 + kq0)]);
        f32x4 d = {0.f, 0.f, 0.f, 0.f};
        d = mfma16(aq0, b0, d);
        d = mfma16(aq1, b1, d);
        dots[t] = d;
    }
    // ---- rel-bias gather (shift trick) + masks ----
    #pragma unroll
    for (int t = 0; t < 16; ++t) {
        const int j = t * 16 + jlane;
        #pragma unroll
        for (int r = 0; r < 4; ++r) {
            const int i  = ibase + r;
            const int dd = j - i;            // key relpos - 128
            float x;
            if (dd > BS) {
                x = -FLT_MAX;                // causal
            } else {
                x = dots[t][r] + bf2f(sE[swzE(dd + BS - 1, i)]);  // + emb[i][j-i+127]
                if (dd == BS) x = -50000.0f; // self-attn mask
            }
            if (n == 0 && j < BS) x = -FLT_MAX;  // look-around padding
            dots[t][r] = x;
        }
    }

    __syncthreads();  // all emb reads complete before P overwrites sE

    // ---- softmax (rows live in 16-lane groups) ----
    float mx[4] = {-FLT_MAX, -FLT_MAX, -FLT_MAX, -FLT_MAX};
    #pragma unroll
    for (int t = 0; t < 16; ++t)
        #pragma unroll
        for (int r = 0; r < 4; ++r) mx[r] = fmaxf(mx[r], dots[t][r]);
    #pragma unroll
    for (int r = 0; r < 4; ++r) {
        mx[r] = fmaxf(mx[r], __shfl_xor(mx[r], 1));
        mx[r] = fmaxf(mx[r], __shfl_xor(mx[r], 2));
        mx[r] = fmaxf(mx[r], __shfl_xor(mx[r], 4));
        mx[r] = fmaxf(mx[r], __shfl_xor(mx[r], 8));
    }
    float sm[4] = {0.f, 0.f, 0.f, 0.f};
    #pragma unroll
    for (int t = 0; t < 16; ++t)
        #pragma unroll
        for (int r = 0; r < 4; ++r) {
            const float pe = __expf(dots[t][r] - mx[r]);
            dots[t][r] = pe;
            sm[r] += pe;
        }
    #pragma unroll
    for (int r = 0; r < 4; ++r) {
        sm[r] += __shfl_xor(sm[r], 1);
        sm[r] += __shfl_xor(sm[r], 2);
        sm[r] += __shfl_xor(sm[r], 4);
        sm[r] += __shfl_xor(sm[r], 8);
        sm[r] = 1.0f / sm[r];
    }
    // ---- write P (bf16, row-major, own-wave rows only) ----
    #pragma unroll
    for (int t = 0; t < 16; ++t) {
        const int j = t * 16 + jlane;
        #pragma unroll
        for (int r = 0; r < 4; ++r)
            sE[swzP(ibase + r, j)] = bfbits(dots[t][r]);
    }

    // ---- phase 3: out = P * V  (A rows = own wave rows; no barrier needed) ----
    f32x4 o[4] = {};
    #pragma unroll
    for (int kt = 0; kt < 8; ++kt) {
        const bf16x8 pa = *reinterpret_cast<const bf16x8*>(&sE[swzP(arow, kt * 32 + kq0)]);
        #pragma unroll
        for (int ct = 0; ct < 4; ++ct) {
            const bf16x8 vb = *reinterpret_cast<const bf16x8*>(&sV[swzV(ct * 16 + jlane, kt * 32 + kq0)]);
            o[ct] = mfma16(pa, vb, o[ct]);
        }
    }

    // ---- epilogue: normalize rows, store fp32 ----
    float* Op = outg + ((size_t)bh * TSEQ + (size_t)n * BS) * EDIM;
    #pragma unroll
    for (int ct = 0; ct < 4; ++ct)
        #pragma unroll
        for (int r = 0; r < 4; ++r)
            Op[(ibase + r) * EDIM + ct * 16 + jlane] = o[ct][r] * sm[r];
}

extern "C" void kernel_launch(void* const* d_in, const int* in_sizes, int n_in,
                              void* d_out, int out_size, void* d_ws, size_t ws_size,
                              hipStream_t stream) {
    const float* q  = (const float*)d_in[0];
    const float* k  = (const float*)d_in[1];
    const float* v  = (const float*)d_in[2];
    const float* rw = (const float*)d_in[3];
    float* out = (float*)d_out;
    local_attn_kernel<<<dim3(1024), dim3(512), 0, stream>>>(q, k, v, rw, out);
}